// Round 12
// baseline (394.219 us; speedup 1.0000x reference)
//
#include <hip/hip_runtime.h>
#include <hip/hip_fp16.h>

typedef int v4i __attribute__((ext_vector_type(4)));

#define AS1C(p) ((const __attribute__((address_space(1))) void*)(p))
#define AS3(p)  ((__attribute__((address_space(3))) void*)(p))

// ---------------------------------------------------------------------------
// 128x128 int8 GEMM tile, 8 waves (2M x 4N, wave tile 64x32), BK=64B,
// mfma_i32_16x16x64_i8, 32KB double-buffered LDS, __syncthreads per K-step.
// Same LDS bytes/iter as the 4-wave r8 frame, but 2 waves/SIMD in-block and
// up to 4 blocks/CU (LDS 32KB, VGPR ~90) -> double the resident-wave pool to
// cover the barrier->ds_read->MFMA dependency chain (the measured wall:
// nothing saturated, occupancy pinned at 33%).
// Hoisted staging pointers (sp[i]+=64). Global-side 16B-slot XOR swizzle with
// reader involution (0 conflicts r2-r9). Column-chunked bijective XCD swizzle.
// EPI 0: fc1 (dequant+bias -> fp16 -> GELU -> gout fp16 + atomicMax amax)
// EPI 1: fc2 (dequant with fp16(amax/127)+bias -> fp16-rounded f32 out)
// ---------------------------------------------------------------------------
template <int EPI>
__launch_bounds__(512, 2)
__global__ void gemm8w(const signed char* __restrict__ A, const signed char* __restrict__ Bw,
                       int M, int N, int K,
                       const float* __restrict__ scale_tok, const float* __restrict__ wsc,
                       const float* __restrict__ bias,
                       __half* __restrict__ gout, unsigned int* __restrict__ amax,
                       float* __restrict__ fout) {
  __shared__ __align__(16) char smem[2][16384];   // per buf: A 8KB | B 8KB
  const int tid = threadIdx.x;
  const int lane = tid & 63, wave = tid >> 6;
  const int wavem = wave >> 2, waven = wave & 3;   // 2M x 4N
  const int lh = lane & 15, sseg = lane >> 4;

  // column-chunked bijective XCD swizzle: consecutive lid share n0 (B panel)
  const int gy = gridDim.y;
  int lid;
  {
    const int o = blockIdx.y * gridDim.x + blockIdx.x;
    const int nwg = gridDim.x * gy;
    const int q = nwg >> 3, r = nwg & 7;
    const int x = o & 7, p = o >> 3;
    lid = (x < r ? x * (q + 1) : r * (q + 1) + (x - r) * q) + p;
  }
  const long long t0 = (long long)(lid % gy) * 128;
  const long long n0 = (long long)(lid / gy) * 128;
  const int nk = K >> 6;
  const long long Mm1 = M - 1, Nm1 = N - 1;

  // ---- hoisted staging pointers: 2 chunks/wave (16 chunks = A 8 + B 8)
  const signed char* sp[2];
  int dst[2];
#pragma unroll
  for (int i = 0; i < 2; ++i) {
    const int c = wave * 2 + i;
    const bool isA = c < 8;
    const int cc = isA ? c : c - 8;
    const int lr = cc * 16 + (lane >> 2);           // tile-local row
    const int gslot = (((lane & 3) ^ ((lr >> 1) & 3)) << 4);
    long long gr = (isA ? t0 : n0) + lr;
    const long long rmax = isA ? Mm1 : Nm1;
    if (gr > rmax) gr = rmax;
    sp[i] = (isA ? A : Bw) + gr * (long long)K + gslot;
    dst[i] = (isA ? 0 : 8192) + cc * 1024;
  }

#define STAGE(bi) do { \
    _Pragma("unroll") \
    for (int i = 0; i < 2; ++i) { \
      __builtin_amdgcn_global_load_lds(AS1C(sp[i]), AS3(&smem[bi][dst[i]]), 16, 0, 0); \
      sp[i] += 64; \
    } \
  } while (0)

  // ---- reader offsets (XOR involution; swz depends only on lh)
  const int xs = ((sseg ^ ((lh >> 1) & 3)) << 4);
  const int offA = wavem * 4096 + lh * 64 + xs;          // + mi*1024, mi<4
  const int offB = 8192 + waven * 2048 + lh * 64 + xs;   // + ni*1024, ni<2

  v4i acc[4][2] = {};

  STAGE(0);
  __syncthreads();

  int cur = 0;
  for (int kt = 0; kt < nk; ++kt) {
    if (kt + 1 < nk) STAGE(cur ^ 1);
    const char* base = smem[cur];
    v4i af[4], bf[2];
#pragma unroll
    for (int mi = 0; mi < 4; ++mi) af[mi] = *(const v4i*)(base + offA + mi * 1024);
#pragma unroll
    for (int ni = 0; ni < 2; ++ni) bf[ni] = *(const v4i*)(base + offB + ni * 1024);
#pragma unroll
    for (int mi = 0; mi < 4; ++mi)
#pragma unroll
      for (int ni = 0; ni < 2; ++ni)
        acc[mi][ni] = __builtin_amdgcn_mfma_i32_16x16x64_i8(af[mi], bf[ni], acc[mi][ni], 0, 0, 0);
    __syncthreads();
    cur ^= 1;
  }
#undef STAGE

  // ---- epilogue (wave owns rows wavem*64+, cols waven*32+)
  long long cidx[2]; float w2[2], bi2[2]; bool cok[2];
#pragma unroll
  for (int ni = 0; ni < 2; ++ni) {
    cidx[ni] = n0 + waven * 32 + ni * 16 + lh;
    cok[ni] = cidx[ni] < N;
    w2[ni] = cok[ni] ? wsc[cidx[ni]] : 0.f;
    bi2[ni] = cok[ni] ? bias[cidx[ni]] : 0.f;
  }
  if (EPI == 0) {
#pragma unroll
    for (int mi = 0; mi < 4; ++mi) {
#pragma unroll
      for (int j = 0; j < 4; ++j) {
        const long long t = t0 + wavem * 64 + mi * 16 + (lane >> 4) * 4 + j;
        const bool valid = t < M;
        const float st = valid ? scale_tok[t] : 0.f;
        float rowmax = 0.f;
#pragma unroll
        for (int ni = 0; ni < 2; ++ni) {
          float v = (float)acc[mi][ni][j] * st * w2[ni] + bi2[ni];
          v = __half2float(__float2half(v));  // fc1 rounds to fp16 (reference)
          const float gl = 0.5f * v * (1.f + erff(v * 0.70710678118654752f));
          rowmax = fmaxf(rowmax, fabsf(gl));
          if (valid && cok[ni]) gout[t * (long long)N + cidx[ni]] = __float2half(gl);
        }
#pragma unroll
        for (int m = 1; m < 16; m <<= 1) rowmax = fmaxf(rowmax, __shfl_xor(rowmax, m));
        if (valid && lh == 0) atomicMax(&amax[t], __float_as_uint(rowmax));
      }
    }
  } else {
#pragma unroll
    for (int mi = 0; mi < 4; ++mi) {
#pragma unroll
      for (int j = 0; j < 4; ++j) {
        const long long t = t0 + wavem * 64 + mi * 16 + (lane >> 4) * 4 + j;
        if (t < M) {
          const float am = __uint_as_float(amax[t]);
          const float st = __half2float(__float2half(am * (1.f / 127.f)));
#pragma unroll
          for (int ni = 0; ni < 2; ++ni) {
            const float v = (float)acc[mi][ni][j] * st * w2[ni] + bi2[ni];
            if (cok[ni]) fout[t * (long long)N + cidx[ni]] = __half2float(__float2half(v));
          }
        }
      }
    }
  }
}

// ---------------------------------------------------------------------------
// int32 -> int8 packing for x, w1, w2 (+ zero the amax buffer each call)
// ---------------------------------------------------------------------------
__global__ void pack_all(const int* __restrict__ a, const int* __restrict__ b,
                         const int* __restrict__ c,
                         signed char* __restrict__ pa, signed char* __restrict__ pb,
                         signed char* __restrict__ pc,
                         unsigned int* __restrict__ amax,
                         long long na, long long nb, long long nc, int T) {
  const long long gid = blockIdx.x * (long long)blockDim.x + threadIdx.x;
  if (gid < T) amax[gid] = 0u;
  const long long n4a = na >> 2, n4b = nb >> 2, n4c = nc >> 2;
  const long long tot = n4a + n4b + n4c;
  const long long stride = (long long)gridDim.x * blockDim.x;
  for (long long u = gid; u < tot; u += stride) {
    const int* src; signed char* dst; long long loc;
    if (u < n4a)            { src = a; dst = pa; loc = u; }
    else if (u < n4a + n4b) { src = b; dst = pb; loc = u - n4a; }
    else                    { src = c; dst = pc; loc = u - n4a - n4b; }
    const int4 v = *(const int4*)(src + (loc << 2));
    const unsigned out = (unsigned)(v.x & 0xff) | ((unsigned)(v.y & 0xff) << 8) |
                         ((unsigned)(v.z & 0xff) << 16) | ((unsigned)(v.w & 0xff) << 24);
    *(unsigned*)(dst + (loc << 2)) = out;
  }
}

// ---------------------------------------------------------------------------
// per-token dynamic int8 quantization of the GELU output
// ---------------------------------------------------------------------------
__global__ void gelu_quant(const __half* __restrict__ g, const unsigned int* __restrict__ amax,
                           signed char* __restrict__ q, long long total, int I) {
  const long long nchunk = total >> 3;
  const long long stride = (long long)gridDim.x * blockDim.x;
  for (long long c = blockIdx.x * (long long)blockDim.x + threadIdx.x; c < nchunk; c += stride) {
    const long long base = c << 3;  // 8 elems, never crosses a row (I % 8 == 0)
    const int t = (int)(base / I);
    const float am = __uint_as_float(amax[t]);
    const float s = fmaxf(__half2float(__float2half(am * (1.f / 127.f))), 1e-8f);
    const float inv = 1.f / s;
    const int4 raw = *(const int4*)(g + base);
    const __half2* h2 = (const __half2*)&raw;
    union { signed char b[8]; int2 v; } u;
#pragma unroll
    for (int k = 0; k < 4; ++k) {
      const float2 f = __half22float2(h2[k]);
      const float q0 = fminf(fmaxf(rintf(f.x * inv), -128.f), 127.f);
      const float q1 = fminf(fmaxf(rintf(f.y * inv), -128.f), 127.f);
      u.b[k * 2]     = (signed char)(int)q0;
      u.b[k * 2 + 1] = (signed char)(int)q1;
    }
    *(int2*)(q + base) = u.v;
  }
}

extern "C" void kernel_launch(void* const* d_in, const int* in_sizes, int n_in,
                              void* d_out, int out_size, void* d_ws, size_t ws_size,
                              hipStream_t stream) {
  const int* hs = (const int*)d_in[0];
  const float* scale_in = (const float*)d_in[1];   // fp16 in reference -> f32 buffer
  const int* w1 = (const int*)d_in[2];
  const float* w1s = (const float*)d_in[3];
  const float* b1 = (const float*)d_in[4];
  const int* w2 = (const int*)d_in[5];
  const float* w2s = (const float*)d_in[6];
  const float* b2 = (const float*)d_in[7];

  const int T = in_sizes[1];        // 2050
  const int I = in_sizes[3];        // 12800
  const int H = in_sizes[6];        // 3200

  char* ws = (char*)d_ws;
  unsigned int* amax = (unsigned int*)ws;                    // T u32 (16KB pad)
  signed char* px  = (signed char*)(ws + 16384);             // T*H
  signed char* pw1 = px + (size_t)T * H;                     // I*H
  signed char* pw2 = pw1 + (size_t)I * H;                    // H*I
  __half* gbuf = (__half*)(pw2 + (size_t)H * I);             // T*I fp16
  signed char* qbuf = (signed char*)(gbuf + (size_t)T * I);  // T*I

  const long long nx = (long long)T * H, nw1 = (long long)I * H, nw2 = (long long)H * I;

  pack_all<<<2048, 256, 0, stream>>>(hs, w1, w2, px, pw1, pw2, amax, nx, nw1, nw2, T);

  // fc1: 128x128 tiles, grid 100 x 17 = 1700 blocks, 512 threads
  dim3 g1(I / 128, (T + 127) / 128);
  gemm8w<0><<<g1, 512, 0, stream>>>(px, pw1, T, I, H, scale_in, w1s, b1, gbuf, amax, nullptr);

  gelu_quant<<<2048, 256, 0, stream>>>(gbuf, amax, qbuf, (long long)T * I, I);

  // fc2: 128x128 tiles, grid 25 x 17 = 425 blocks
  dim3 g2(H / 128, (T + 127) / 128);
  gemm8w<1><<<g2, 512, 0, stream>>>(qbuf, pw2, T, H, I, nullptr, w2s, b2, nullptr, amax, (float*)d_out);
}

// Round 13
// 374.714 us; speedup vs baseline: 1.0521x; 1.0521x over previous
//
#include <hip/hip_runtime.h>
#include <hip/hip_fp16.h>

typedef int v4i __attribute__((ext_vector_type(4)));

#define AS1C(p) ((const __attribute__((address_space(1))) void*)(p))
#define AS3(p)  ((__attribute__((address_space(3))) void*)(p))

// ---------------------------------------------------------------------------
// fc1: 256x256 int8 GEMM tile, 16 waves (1024 thr, 4M x 4N, wave tile 64x64),
// BK=64B, mfma_i32_16x16x64_i8, 2x32KB double-buffer, __syncthreads drain.
// Rationale (r2..r12 normalization): global_load_lds service is ~12-13 B/cyc
// per CU when >=10 waves issue; ops/cyc = staging-rate x tile-intensity.
// 128^2 tiles (128 ops/B) pin at ~1700 ops/cyc regardless of schedule; 256^2
// doubles intensity but previously always ran 1 starved block (ring-3/4 LDS).
// This config: 256^2 intensity AND 16 resident waves via 64KB total LDS.
// Phased b-reads (bf01 -> 8 MFMA -> bf23 -> 8 MFMA) keep live regs <= ~124
// for the mandatory 4 waves/SIMD (launch_bounds(1024,4) caps at 128).
// ---------------------------------------------------------------------------
__launch_bounds__(1024, 4)
__global__ void gemm256(const signed char* __restrict__ A, const signed char* __restrict__ Bw,
                        int M, int N, int K,
                        const float* __restrict__ scale_tok, const float* __restrict__ wsc,
                        const float* __restrict__ bias,
                        __half* __restrict__ gout, unsigned int* __restrict__ amax) {
  __shared__ __align__(16) char smem[2][32768];   // per buf: A 16KB | B 16KB
  const int tid = threadIdx.x;
  const int lane = tid & 63, wave = tid >> 6;      // 0..15
  const int wavem = wave >> 2, waven = wave & 3;   // 4M x 4N
  const int lh = lane & 15, sseg = lane >> 4;

  // column-chunked bijective XCD swizzle: consecutive lid share n0 (B panel)
  const int gy = gridDim.y;
  int lid;
  {
    const int o = blockIdx.y * gridDim.x + blockIdx.x;
    const int nwg = gridDim.x * gy;
    const int q = nwg >> 3, r = nwg & 7;
    const int x = o & 7, p = o >> 3;
    lid = (x < r ? x * (q + 1) : r * (q + 1) + (x - r) * q) + p;
  }
  const long long t0 = (long long)(lid % gy) * 256;
  const long long n0 = (long long)(lid / gy) * 256;
  const int nk = K >> 6;
  const long long Mm1 = M - 1, Nm1 = N - 1;

  // ---- hoisted staging pointers: 2 loads/thread (A chunk `wave`, B chunk `wave`)
  const int lr4 = lane >> 2, slot = lane & 3;
  const int rloc = wave * 16 + lr4;                      // tile-local row 0-255
  const int gslot = (slot ^ ((rloc >> 1) & 3)) << 4;     // global-side XOR
  const signed char* sp0;
  const signed char* sp1;
  {
    long long gr = t0 + rloc; if (gr > Mm1) gr = Mm1;
    sp0 = A + gr * (long long)K + gslot;
    long long gn = n0 + rloc; if (gn > Nm1) gn = Nm1;
    sp1 = Bw + gn * (long long)K + gslot;
  }
  const int d0 = wave * 1024, d1 = 16384 + wave * 1024;

#define STAGE(bi) do { \
    __builtin_amdgcn_global_load_lds(AS1C(sp0), AS3(&smem[bi][d0]), 16, 0, 0); sp0 += 64; \
    __builtin_amdgcn_global_load_lds(AS1C(sp1), AS3(&smem[bi][d1]), 16, 0, 0); sp1 += 64; \
  } while (0)

  // ---- reader offsets (XOR involution; swz depends only on lh)
  const int xs = ((sseg ^ ((lh >> 1) & 3)) << 4);
  const int offA = wavem * 4096 + lh * 64 + xs;           // + mi*1024, mi<4
  const int offB = 16384 + waven * 4096 + lh * 64 + xs;   // + ni*1024, ni<4

  v4i acc[4][4] = {};

  STAGE(0);
  __syncthreads();

  int cur = 0;
  for (int kt = 0; kt < nk; ++kt) {
    if (kt + 1 < nk) STAGE(cur ^ 1);
    const char* base = smem[cur];
    v4i af[4], bf[2];
#pragma unroll
    for (int mi = 0; mi < 4; ++mi) af[mi] = *(const v4i*)(base + offA + mi * 1024);
    // phase 1: b0,b1
    bf[0] = *(const v4i*)(base + offB);
    bf[1] = *(const v4i*)(base + offB + 1024);
#pragma unroll
    for (int mi = 0; mi < 4; ++mi) {
      acc[mi][0] = __builtin_amdgcn_mfma_i32_16x16x64_i8(af[mi], bf[0], acc[mi][0], 0, 0, 0);
      acc[mi][1] = __builtin_amdgcn_mfma_i32_16x16x64_i8(af[mi], bf[1], acc[mi][1], 0, 0, 0);
    }
    // phase 2: b2,b3 (reuses bf regs -> live set stays under the 128 cap)
    bf[0] = *(const v4i*)(base + offB + 2048);
    bf[1] = *(const v4i*)(base + offB + 3072);
#pragma unroll
    for (int mi = 0; mi < 4; ++mi) {
      acc[mi][2] = __builtin_amdgcn_mfma_i32_16x16x64_i8(af[mi], bf[0], acc[mi][2], 0, 0, 0);
      acc[mi][3] = __builtin_amdgcn_mfma_i32_16x16x64_i8(af[mi], bf[1], acc[mi][3], 0, 0, 0);
    }
    __syncthreads();
    cur ^= 1;
  }
#undef STAGE

  // ---- fc1 epilogue: dequant+bias -> fp16 -> GELU -> gout + atomicMax amax
  long long cidx[4]; float w4[4], bi4[4]; bool cok[4];
#pragma unroll
  for (int ni = 0; ni < 4; ++ni) {
    cidx[ni] = n0 + waven * 64 + ni * 16 + lh;
    cok[ni] = cidx[ni] < N;
    w4[ni] = cok[ni] ? wsc[cidx[ni]] : 0.f;
    bi4[ni] = cok[ni] ? bias[cidx[ni]] : 0.f;
  }
#pragma unroll
  for (int mi = 0; mi < 4; ++mi) {
#pragma unroll
    for (int j = 0; j < 4; ++j) {
      const long long t = t0 + wavem * 64 + mi * 16 + (lane >> 4) * 4 + j;
      const bool valid = t < M;
      const float st = valid ? scale_tok[t] : 0.f;
      float rowmax = 0.f;
#pragma unroll
      for (int ni = 0; ni < 4; ++ni) {
        float v = (float)acc[mi][ni][j] * st * w4[ni] + bi4[ni];
        v = __half2float(__float2half(v));  // fc1 rounds to fp16 (reference)
        const float gl = 0.5f * v * (1.f + erff(v * 0.70710678118654752f));
        rowmax = fmaxf(rowmax, fabsf(gl));
        if (valid && cok[ni]) gout[t * (long long)N + cidx[ni]] = __float2half(gl);
      }
#pragma unroll
      for (int m = 1; m < 16; m <<= 1) rowmax = fmaxf(rowmax, __shfl_xor(rowmax, m));
      if (valid && lh == 0) atomicMax(&amax[t], __float_as_uint(rowmax));
    }
  }
}

// ---------------------------------------------------------------------------
// fc2: r8-exact 128x128 / 4-wave / 32KB dbuf kernel (165 us measured; hedge)
// ---------------------------------------------------------------------------
__device__ __forceinline__ void stage_tile(const signed char* __restrict__ g, long long ld,
                                           long long rmax, long long r0, int k0,
                                           char* lds, int tid) {
  const int wave = tid >> 6, lane = tid & 63;
#pragma unroll
  for (int p = 0; p < 2; ++p) {
    const int chunk = wave * 2 + p;
    const int row = chunk * 16 + (lane >> 2);
    const int slot = lane & 3;
    const int gslot = slot ^ ((row >> 1) & 3);
    long long rg = r0 + row;
    if (rg > rmax) rg = rmax;
    const signed char* src = g + rg * ld + (long long)k0 + gslot * 16;
    char* dst = lds + chunk * 1024;
    __builtin_amdgcn_global_load_lds(AS1C(src), AS3(dst), 16, 0, 0);
  }
}

__launch_bounds__(256, 4)
__global__ void gemm_fc2(const signed char* __restrict__ A, const signed char* __restrict__ Bw,
                         int M, int N, int K,
                         const float* __restrict__ wsc, const float* __restrict__ bias,
                         unsigned int* __restrict__ amax, float* __restrict__ fout) {
  __shared__ __align__(16) char lds[2][2][128 * 64];
  const int tid = threadIdx.x;
  const int lane = tid & 63, wave = tid >> 6;
  const int wrow = (wave >> 1) * 64, wcol = (wave & 1) * 64;

  const int gy = gridDim.y;
  int lid;
  {
    const int o = blockIdx.y * gridDim.x + blockIdx.x;
    const int nwg = gridDim.x * gy;
    const int q = nwg >> 3, r = nwg & 7;
    const int x = o & 7, p = o >> 3;
    lid = (x < r ? x * (q + 1) : r * (q + 1) + (x - r) * q) + p;
  }
  const long long t0 = (long long)(lid % gy) * 128;
  const long long n0 = (long long)(lid / gy) * 128;

  v4i acc[4][4] = {};

  stage_tile(A, K, (long long)M - 1, t0, 0, lds[0][0], tid);
  stage_tile(Bw, K, (long long)N - 1, n0, 0, lds[0][1], tid);
  __syncthreads();

  const int nk = K >> 6;
  int cur = 0;
  const int srow = lane & 15, sseg = lane >> 4;
  for (int kt = 0; kt < nk; ++kt) {
    if (kt + 1 < nk) {
      stage_tile(A, K, (long long)M - 1, t0, (kt + 1) << 6, lds[cur ^ 1][0], tid);
      stage_tile(Bw, K, (long long)N - 1, n0, (kt + 1) << 6, lds[cur ^ 1][1], tid);
    }
    v4i af[4], bf[4];
#pragma unroll
    for (int mi = 0; mi < 4; ++mi) {
      const int r = wrow + mi * 16 + srow;
      const int sl = sseg ^ ((r >> 1) & 3);
      af[mi] = *(const v4i*)&lds[cur][0][r * 64 + sl * 16];
    }
#pragma unroll
    for (int ni = 0; ni < 4; ++ni) {
      const int r = wcol + ni * 16 + srow;
      const int sl = sseg ^ ((r >> 1) & 3);
      bf[ni] = *(const v4i*)&lds[cur][1][r * 64 + sl * 16];
    }
#pragma unroll
    for (int mi = 0; mi < 4; ++mi)
#pragma unroll
      for (int ni = 0; ni < 4; ++ni)
        acc[mi][ni] = __builtin_amdgcn_mfma_i32_16x16x64_i8(af[mi], bf[ni], acc[mi][ni], 0, 0, 0);
    __syncthreads();
    cur ^= 1;
  }

#pragma unroll
  for (int mi = 0; mi < 4; ++mi) {
#pragma unroll
    for (int j = 0; j < 4; ++j) {
      const long long t = t0 + wrow + mi * 16 + (lane >> 4) * 4 + j;
      if (t < M) {
        const float am = __uint_as_float(amax[t]);
        const float st = __half2float(__float2half(am * (1.f / 127.f)));
#pragma unroll
        for (int ni = 0; ni < 4; ++ni) {
          const long long c = n0 + wcol + ni * 16 + (lane & 15);
          const float v = (float)acc[mi][ni][j] * st * wsc[c] + bias[c];
          fout[t * (long long)N + c] = __half2float(__float2half(v));
        }
      }
    }
  }
}

// ---------------------------------------------------------------------------
// int32 -> int8 packing for x, w1, w2 (+ zero the amax buffer each call)
// ---------------------------------------------------------------------------
__global__ void pack_all(const int* __restrict__ a, const int* __restrict__ b,
                         const int* __restrict__ c,
                         signed char* __restrict__ pa, signed char* __restrict__ pb,
                         signed char* __restrict__ pc,
                         unsigned int* __restrict__ amax,
                         long long na, long long nb, long long nc, int T) {
  const long long gid = blockIdx.x * (long long)blockDim.x + threadIdx.x;
  if (gid < T) amax[gid] = 0u;
  const long long n4a = na >> 2, n4b = nb >> 2, n4c = nc >> 2;
  const long long tot = n4a + n4b + n4c;
  const long long stride = (long long)gridDim.x * blockDim.x;
  for (long long u = gid; u < tot; u += stride) {
    const int* src; signed char* dst; long long loc;
    if (u < n4a)            { src = a; dst = pa; loc = u; }
    else if (u < n4a + n4b) { src = b; dst = pb; loc = u - n4a; }
    else                    { src = c; dst = pc; loc = u - n4a - n4b; }
    const int4 v = *(const int4*)(src + (loc << 2));
    const unsigned out = (unsigned)(v.x & 0xff) | ((unsigned)(v.y & 0xff) << 8) |
                         ((unsigned)(v.z & 0xff) << 16) | ((unsigned)(v.w & 0xff) << 24);
    *(unsigned*)(dst + (loc << 2)) = out;
  }
}

// ---------------------------------------------------------------------------
// per-token dynamic int8 quantization of the GELU output
// ---------------------------------------------------------------------------
__global__ void gelu_quant(const __half* __restrict__ g, const unsigned int* __restrict__ amax,
                           signed char* __restrict__ q, long long total, int I) {
  const long long nchunk = total >> 3;
  const long long stride = (long long)gridDim.x * blockDim.x;
  for (long long c = blockIdx.x * (long long)blockDim.x + threadIdx.x; c < nchunk; c += stride) {
    const long long base = c << 3;  // 8 elems, never crosses a row (I % 8 == 0)
    const int t = (int)(base / I);
    const float am = __uint_as_float(amax[t]);
    const float s = fmaxf(__half2float(__float2half(am * (1.f / 127.f))), 1e-8f);
    const float inv = 1.f / s;
    const int4 raw = *(const int4*)(g + base);
    const __half2* h2 = (const __half2*)&raw;
    union { signed char b[8]; int2 v; } u;
#pragma unroll
    for (int k = 0; k < 4; ++k) {
      const float2 f = __half22float2(h2[k]);
      const float q0 = fminf(fmaxf(rintf(f.x * inv), -128.f), 127.f);
      const float q1 = fminf(fmaxf(rintf(f.y * inv), -128.f), 127.f);
      u.b[k * 2]     = (signed char)(int)q0;
      u.b[k * 2 + 1] = (signed char)(int)q1;
    }
    *(int2*)(q + base) = u.v;
  }
}

extern "C" void kernel_launch(void* const* d_in, const int* in_sizes, int n_in,
                              void* d_out, int out_size, void* d_ws, size_t ws_size,
                              hipStream_t stream) {
  const int* hs = (const int*)d_in[0];
  const float* scale_in = (const float*)d_in[1];   // fp16 in reference -> f32 buffer
  const int* w1 = (const int*)d_in[2];
  const float* w1s = (const float*)d_in[3];
  const float* b1 = (const float*)d_in[4];
  const int* w2 = (const int*)d_in[5];
  const float* w2s = (const float*)d_in[6];
  const float* b2 = (const float*)d_in[7];

  const int T = in_sizes[1];        // 2050
  const int I = in_sizes[3];        // 12800
  const int H = in_sizes[6];        // 3200

  char* ws = (char*)d_ws;
  unsigned int* amax = (unsigned int*)ws;                    // T u32 (16KB pad)
  signed char* px  = (signed char*)(ws + 16384);             // T*H
  signed char* pw1 = px + (size_t)T * H;                     // I*H
  signed char* pw2 = pw1 + (size_t)I * H;                    // H*I
  __half* gbuf = (__half*)(pw2 + (size_t)H * I);             // T*I fp16
  signed char* qbuf = (signed char*)(gbuf + (size_t)T * I);  // T*I

  const long long nx = (long long)T * H, nw1 = (long long)I * H, nw2 = (long long)H * I;

  pack_all<<<2048, 256, 0, stream>>>(hs, w1, w2, px, pw1, pw2, amax, nx, nw1, nw2, T);

  // fc1: 256x256 tiles, 16 waves, grid 50 x 9 = 450 blocks
  dim3 g1(I / 256, (T + 255) / 256);
  gemm256<<<g1, 1024, 0, stream>>>(px, pw1, T, I, H, scale_in, w1s, b1, gbuf, amax);

  gelu_quant<<<2048, 256, 0, stream>>>(gbuf, amax, qbuf, (long long)T * I, I);

  // fc2: r8-exact 128x128, grid 25 x 17 = 425 blocks
  dim3 g2(H / 128, (T + 127) / 128);
  gemm_fc2<<<g2, 256, 0, stream>>>(qbuf, pw2, T, H, I, w2s, b2, amax, (float*)d_out);
}

// Round 14
// 366.258 us; speedup vs baseline: 1.0763x; 1.0231x over previous
//
#include <hip/hip_runtime.h>
#include <hip/hip_fp16.h>

typedef int v4i __attribute__((ext_vector_type(4)));

#define AS1C(p) ((const __attribute__((address_space(1))) void*)(p))
#define AS3(p)  ((__attribute__((address_space(3))) void*)(p))

// ---------------------------------------------------------------------------
// pack1: int32->int8 for x and w1 + zero amax. Runs before fc1 (~190 MB).
// ---------------------------------------------------------------------------
__global__ void pack1(const int* __restrict__ a, const int* __restrict__ b,
                      signed char* __restrict__ pa, signed char* __restrict__ pb,
                      unsigned int* __restrict__ amax,
                      long long na, long long nb, int T) {
  const long long gid = blockIdx.x * (long long)blockDim.x + threadIdx.x;
  if (gid < T) amax[gid] = 0u;
  const long long n4a = na >> 2, n4b = nb >> 2;
  const long long tot = n4a + n4b;
  const long long stride = (long long)gridDim.x * blockDim.x;
  for (long long u = gid; u < tot; u += stride) {
    const int* src; signed char* dst; long long loc;
    if (u < n4a) { src = a; dst = pa; loc = u; }
    else         { src = b; dst = pb; loc = u - n4a; }
    const int4 v = *(const int4*)(src + (loc << 2));
    const unsigned out = (unsigned)(v.x & 0xff) | ((unsigned)(v.y & 0xff) << 8) |
                         ((unsigned)(v.z & 0xff) << 16) | ((unsigned)(v.w & 0xff) << 24);
    *(unsigned*)(dst + (loc << 2)) = out;
  }
}

// ---------------------------------------------------------------------------
// fc1 fused: blocks [0,npack) pack w2 int32->int8 (grid-stride, dispatched
// first so the streaming overlaps the GEMM); blocks [npack, npack+450) run
// the r13-best 256x256 / 16-wave / 64KB-dbuf fc1 GEMM.
// fc1 is latency-bound (HBM 12%) -> co-resident pack blocks use idle BW.
// w2 is consumed only by fc2 (next launch, stream-ordered) -> no race.
// ---------------------------------------------------------------------------
__launch_bounds__(1024, 4)
__global__ void fc1_fused(const signed char* __restrict__ A, const signed char* __restrict__ Bw,
                          int M, int N, int K,
                          const float* __restrict__ scale_tok, const float* __restrict__ wsc,
                          const float* __restrict__ bias,
                          __half* __restrict__ gout, unsigned int* __restrict__ amax,
                          const int* __restrict__ w2src, signed char* __restrict__ w2dst,
                          long long n4w2, int npack, int gy) {
  __shared__ __align__(16) char smem[2][32768];   // per buf: A 16KB | B 16KB
  const int bid = blockIdx.x;

  if (bid < npack) {
    // ---- w2 packing (int32 -> int8), 16B-chunk grid-stride
    const long long stride = (long long)npack * 1024;
    for (long long u = (long long)bid * 1024 + threadIdx.x; u < n4w2; u += stride) {
      const int4 v = *(const int4*)(w2src + (u << 2));
      const unsigned out = (unsigned)(v.x & 0xff) | ((unsigned)(v.y & 0xff) << 8) |
                           ((unsigned)(v.z & 0xff) << 16) | ((unsigned)(v.w & 0xff) << 24);
      *(unsigned*)(w2dst + (u << 2)) = out;
    }
    return;
  }

  // ---- GEMM half (r13-exact 256x256, 16 waves 4Mx4N, wave tile 64x64)
  const int tid = threadIdx.x;
  const int lane = tid & 63, wave = tid >> 6;
  const int wavem = wave >> 2, waven = wave & 3;
  const int lh = lane & 15, sseg = lane >> 4;

  int lid;
  {
    const int o = bid - npack;
    const int nwg = gridDim.x - npack;
    const int q = nwg >> 3, r = nwg & 7;
    const int x = o & 7, p = o >> 3;
    lid = (x < r ? x * (q + 1) : r * (q + 1) + (x - r) * q) + p;
  }
  const long long t0 = (long long)(lid % gy) * 256;
  const long long n0 = (long long)(lid / gy) * 256;
  const int nk = K >> 6;
  const long long Mm1 = M - 1, Nm1 = N - 1;

  const int lr4 = lane >> 2, slot = lane & 3;
  const int rloc = wave * 16 + lr4;
  const int gslot = (slot ^ ((rloc >> 1) & 3)) << 4;
  const signed char* sp0;
  const signed char* sp1;
  {
    long long gr = t0 + rloc; if (gr > Mm1) gr = Mm1;
    sp0 = A + gr * (long long)K + gslot;
    long long gn = n0 + rloc; if (gn > Nm1) gn = Nm1;
    sp1 = Bw + gn * (long long)K + gslot;
  }
  const int d0 = wave * 1024, d1 = 16384 + wave * 1024;

#define STAGE(bi) do { \
    __builtin_amdgcn_global_load_lds(AS1C(sp0), AS3(&smem[bi][d0]), 16, 0, 0); sp0 += 64; \
    __builtin_amdgcn_global_load_lds(AS1C(sp1), AS3(&smem[bi][d1]), 16, 0, 0); sp1 += 64; \
  } while (0)

  const int xs = ((sseg ^ ((lh >> 1) & 3)) << 4);
  const int offA = wavem * 4096 + lh * 64 + xs;
  const int offB = 16384 + waven * 4096 + lh * 64 + xs;

  v4i acc[4][4] = {};

  STAGE(0);
  __syncthreads();

  int cur = 0;
  for (int kt = 0; kt < nk; ++kt) {
    if (kt + 1 < nk) STAGE(cur ^ 1);
    const char* base = smem[cur];
    v4i af[4], bf[2];
#pragma unroll
    for (int mi = 0; mi < 4; ++mi) af[mi] = *(const v4i*)(base + offA + mi * 1024);
    bf[0] = *(const v4i*)(base + offB);
    bf[1] = *(const v4i*)(base + offB + 1024);
#pragma unroll
    for (int mi = 0; mi < 4; ++mi) {
      acc[mi][0] = __builtin_amdgcn_mfma_i32_16x16x64_i8(af[mi], bf[0], acc[mi][0], 0, 0, 0);
      acc[mi][1] = __builtin_amdgcn_mfma_i32_16x16x64_i8(af[mi], bf[1], acc[mi][1], 0, 0, 0);
    }
    bf[0] = *(const v4i*)(base + offB + 2048);
    bf[1] = *(const v4i*)(base + offB + 3072);
#pragma unroll
    for (int mi = 0; mi < 4; ++mi) {
      acc[mi][2] = __builtin_amdgcn_mfma_i32_16x16x64_i8(af[mi], bf[0], acc[mi][2], 0, 0, 0);
      acc[mi][3] = __builtin_amdgcn_mfma_i32_16x16x64_i8(af[mi], bf[1], acc[mi][3], 0, 0, 0);
    }
    __syncthreads();
    cur ^= 1;
  }
#undef STAGE

  long long cidx[4]; float w4[4], bi4[4]; bool cok[4];
#pragma unroll
  for (int ni = 0; ni < 4; ++ni) {
    cidx[ni] = n0 + waven * 64 + ni * 16 + lh;
    cok[ni] = cidx[ni] < N;
    w4[ni] = cok[ni] ? wsc[cidx[ni]] : 0.f;
    bi4[ni] = cok[ni] ? bias[cidx[ni]] : 0.f;
  }
#pragma unroll
  for (int mi = 0; mi < 4; ++mi) {
#pragma unroll
    for (int j = 0; j < 4; ++j) {
      const long long t = t0 + wavem * 64 + mi * 16 + (lane >> 4) * 4 + j;
      const bool valid = t < M;
      const float st = valid ? scale_tok[t] : 0.f;
      float rowmax = 0.f;
#pragma unroll
      for (int ni = 0; ni < 4; ++ni) {
        float v = (float)acc[mi][ni][j] * st * w4[ni] + bi4[ni];
        v = __half2float(__float2half(v));  // fc1 rounds to fp16 (reference)
        const float gl = 0.5f * v * (1.f + erff(v * 0.70710678118654752f));
        rowmax = fmaxf(rowmax, fabsf(gl));
        if (valid && cok[ni]) gout[t * (long long)N + cidx[ni]] = __float2half(gl);
      }
#pragma unroll
      for (int m = 1; m < 16; m <<= 1) rowmax = fmaxf(rowmax, __shfl_xor(rowmax, m));
      if (valid && lh == 0) atomicMax(&amax[t], __float_as_uint(rowmax));
    }
  }
}

// ---------------------------------------------------------------------------
// fc2: r8-exact 128x128 / 4-wave / 32KB dbuf kernel
// ---------------------------------------------------------------------------
__device__ __forceinline__ void stage_tile(const signed char* __restrict__ g, long long ld,
                                           long long rmax, long long r0, int k0,
                                           char* lds, int tid) {
  const int wave = tid >> 6, lane = tid & 63;
#pragma unroll
  for (int p = 0; p < 2; ++p) {
    const int chunk = wave * 2 + p;
    const int row = chunk * 16 + (lane >> 2);
    const int slot = lane & 3;
    const int gslot = slot ^ ((row >> 1) & 3);
    long long rg = r0 + row;
    if (rg > rmax) rg = rmax;
    const signed char* src = g + rg * ld + (long long)k0 + gslot * 16;
    char* dst = lds + chunk * 1024;
    __builtin_amdgcn_global_load_lds(AS1C(src), AS3(dst), 16, 0, 0);
  }
}

__launch_bounds__(256, 4)
__global__ void gemm_fc2(const signed char* __restrict__ A, const signed char* __restrict__ Bw,
                         int M, int N, int K,
                         const float* __restrict__ wsc, const float* __restrict__ bias,
                         unsigned int* __restrict__ amax, float* __restrict__ fout) {
  __shared__ __align__(16) char lds[2][2][128 * 64];
  const int tid = threadIdx.x;
  const int lane = tid & 63, wave = tid >> 6;
  const int wrow = (wave >> 1) * 64, wcol = (wave & 1) * 64;

  const int gy = gridDim.y;
  int lid;
  {
    const int o = blockIdx.y * gridDim.x + blockIdx.x;
    const int nwg = gridDim.x * gy;
    const int q = nwg >> 3, r = nwg & 7;
    const int x = o & 7, p = o >> 3;
    lid = (x < r ? x * (q + 1) : r * (q + 1) + (x - r) * q) + p;
  }
  const long long t0 = (long long)(lid % gy) * 128;
  const long long n0 = (long long)(lid / gy) * 128;

  v4i acc[4][4] = {};

  stage_tile(A, K, (long long)M - 1, t0, 0, lds[0][0], tid);
  stage_tile(Bw, K, (long long)N - 1, n0, 0, lds[0][1], tid);
  __syncthreads();

  const int nk = K >> 6;
  int cur = 0;
  const int srow = lane & 15, sseg = lane >> 4;
  for (int kt = 0; kt < nk; ++kt) {
    if (kt + 1 < nk) {
      stage_tile(A, K, (long long)M - 1, t0, (kt + 1) << 6, lds[cur ^ 1][0], tid);
      stage_tile(Bw, K, (long long)N - 1, n0, (kt + 1) << 6, lds[cur ^ 1][1], tid);
    }
    v4i af[4], bf[4];
#pragma unroll
    for (int mi = 0; mi < 4; ++mi) {
      const int r = wrow + mi * 16 + srow;
      const int sl = sseg ^ ((r >> 1) & 3);
      af[mi] = *(const v4i*)&lds[cur][0][r * 64 + sl * 16];
    }
#pragma unroll
    for (int ni = 0; ni < 4; ++ni) {
      const int r = wcol + ni * 16 + srow;
      const int sl = sseg ^ ((r >> 1) & 3);
      bf[ni] = *(const v4i*)&lds[cur][1][r * 64 + sl * 16];
    }
#pragma unroll
    for (int mi = 0; mi < 4; ++mi)
#pragma unroll
      for (int ni = 0; ni < 4; ++ni)
        acc[mi][ni] = __builtin_amdgcn_mfma_i32_16x16x64_i8(af[mi], bf[ni], acc[mi][ni], 0, 0, 0);
    __syncthreads();
    cur ^= 1;
  }

#pragma unroll
  for (int mi = 0; mi < 4; ++mi) {
#pragma unroll
    for (int j = 0; j < 4; ++j) {
      const long long t = t0 + wrow + mi * 16 + (lane >> 4) * 4 + j;
      if (t < M) {
        const float am = __uint_as_float(amax[t]);
        const float st = __half2float(__float2half(am * (1.f / 127.f)));
#pragma unroll
        for (int ni = 0; ni < 4; ++ni) {
          const long long c = n0 + wcol + ni * 16 + (lane & 15);
          const float v = (float)acc[mi][ni][j] * st * wsc[c] + bias[c];
          fout[t * (long long)N + c] = __half2float(__float2half(v));
        }
      }
    }
  }
}

// ---------------------------------------------------------------------------
// per-token dynamic int8 quantization of the GELU output
// ---------------------------------------------------------------------------
__global__ void gelu_quant(const __half* __restrict__ g, const unsigned int* __restrict__ amax,
                           signed char* __restrict__ q, long long total, int I) {
  const long long nchunk = total >> 3;
  const long long stride = (long long)gridDim.x * blockDim.x;
  for (long long c = blockIdx.x * (long long)blockDim.x + threadIdx.x; c < nchunk; c += stride) {
    const long long base = c << 3;  // 8 elems, never crosses a row (I % 8 == 0)
    const int t = (int)(base / I);
    const float am = __uint_as_float(amax[t]);
    const float s = fmaxf(__half2float(__float2half(am * (1.f / 127.f))), 1e-8f);
    const float inv = 1.f / s;
    const int4 raw = *(const int4*)(g + base);
    const __half2* h2 = (const __half2*)&raw;
    union { signed char b[8]; int2 v; } u;
#pragma unroll
    for (int k = 0; k < 4; ++k) {
      const float2 f = __half22float2(h2[k]);
      const float q0 = fminf(fmaxf(rintf(f.x * inv), -128.f), 127.f);
      const float q1 = fminf(fmaxf(rintf(f.y * inv), -128.f), 127.f);
      u.b[k * 2]     = (signed char)(int)q0;
      u.b[k * 2 + 1] = (signed char)(int)q1;
    }
    *(int2*)(q + base) = u.v;
  }
}

extern "C" void kernel_launch(void* const* d_in, const int* in_sizes, int n_in,
                              void* d_out, int out_size, void* d_ws, size_t ws_size,
                              hipStream_t stream) {
  const int* hs = (const int*)d_in[0];
  const float* scale_in = (const float*)d_in[1];   // fp16 in reference -> f32 buffer
  const int* w1 = (const int*)d_in[2];
  const float* w1s = (const float*)d_in[3];
  const float* b1 = (const float*)d_in[4];
  const int* w2 = (const int*)d_in[5];
  const float* w2s = (const float*)d_in[6];
  const float* b2 = (const float*)d_in[7];

  const int T = in_sizes[1];        // 2050
  const int I = in_sizes[3];        // 12800
  const int H = in_sizes[6];        // 3200

  char* ws = (char*)d_ws;
  unsigned int* amax = (unsigned int*)ws;                    // T u32 (16KB pad)
  signed char* px  = (signed char*)(ws + 16384);             // T*H
  signed char* pw1 = px + (size_t)T * H;                     // I*H
  signed char* pw2 = pw1 + (size_t)I * H;                    // H*I
  __half* gbuf = (__half*)(pw2 + (size_t)H * I);             // T*I fp16
  signed char* qbuf = (signed char*)(gbuf + (size_t)T * I);  // T*I

  const long long nx = (long long)T * H, nw1 = (long long)I * H, nw2 = (long long)H * I;

  // pack x + w1 (+ amax zero) — must precede fc1
  pack1<<<2048, 256, 0, stream>>>(hs, w1, px, pw1, amax, nx, nw1, T);

  // fc1 (256x256, 16 waves) fused with w2 packing (128 pack blocks first)
  const int NPACK = 128;
  const int gy1 = (T + 255) / 256;                 // 9
  const int gemmBlocks = (I / 256) * gy1;          // 450
  fc1_fused<<<NPACK + gemmBlocks, 1024, 0, stream>>>(
      px, pw1, T, I, H, scale_in, w1s, b1, gbuf, amax,
      w2, pw2, nw2 >> 2, NPACK, gy1);

  gelu_quant<<<2048, 256, 0, stream>>>(gbuf, amax, qbuf, (long long)T * I, I);

  // fc2: r8-exact 128x128, grid 25 x 17 = 425 blocks
  dim3 g2(H / 128, (T + 127) / 128);
  gemm_fc2<<<g2, 256, 0, stream>>>(qbuf, pw2, T, H, I, w2s, b2, amax, (float*)d_out);
}

// Round 15
// 334.883 us; speedup vs baseline: 1.1772x; 1.0937x over previous
//
#include <hip/hip_runtime.h>
#include <hip/hip_fp16.h>

typedef int v4i __attribute__((ext_vector_type(4)));

#define AS1C(p) ((const __attribute__((address_space(1))) void*)(p))
#define AS3(p)  ((__attribute__((address_space(3))) void*)(p))

// ---------------------------------------------------------------------------
// pack1: int32->int8 for x and w1 + zero amax. Runs before fc1 (~237 MB).
// ---------------------------------------------------------------------------
__global__ void pack1(const int* __restrict__ a, const int* __restrict__ b,
                      signed char* __restrict__ pa, signed char* __restrict__ pb,
                      unsigned int* __restrict__ amax,
                      long long na, long long nb, int T) {
  const long long gid = blockIdx.x * (long long)blockDim.x + threadIdx.x;
  if (gid < T) amax[gid] = 0u;
  const long long n4a = na >> 2, n4b = nb >> 2;
  const long long tot = n4a + n4b;
  const long long stride = (long long)gridDim.x * blockDim.x;
  for (long long u = gid; u < tot; u += stride) {
    const int* src; signed char* dst; long long loc;
    if (u < n4a) { src = a; dst = pa; loc = u; }
    else         { src = b; dst = pb; loc = u - n4a; }
    const int4 v = *(const int4*)(src + (loc << 2));
    const unsigned out = (unsigned)(v.x & 0xff) | ((unsigned)(v.y & 0xff) << 8) |
                         ((unsigned)(v.z & 0xff) << 16) | ((unsigned)(v.w & 0xff) << 24);
    *(unsigned*)(dst + (loc << 2)) = out;
  }
}

// ---------------------------------------------------------------------------
// fc1 fused: blocks [0,npack) pack w2 int32->int8 (grid-stride, dispatched
// first so streaming overlaps the GEMM); blocks [npack, npack+450) run the
// r13-best 256x256 / 16-wave / 64KB-dbuf fc1 GEMM.
// npack = 62 so npack + 450 = 512 = exact 2-blocks/CU co-residency: no GEMM
// tail (r14's npack=128 serialized 66 GEMM blocks, costing ~30us).
// w2 is consumed only by fc2 (next launch, stream-ordered) -> no race.
// ---------------------------------------------------------------------------
__launch_bounds__(1024, 4)
__global__ void fc1_fused(const signed char* __restrict__ A, const signed char* __restrict__ Bw,
                          int M, int N, int K,
                          const float* __restrict__ scale_tok, const float* __restrict__ wsc,
                          const float* __restrict__ bias,
                          __half* __restrict__ gout, unsigned int* __restrict__ amax,
                          const int* __restrict__ w2src, signed char* __restrict__ w2dst,
                          long long n4w2, int npack, int gy) {
  __shared__ __align__(16) char smem[2][32768];   // per buf: A 16KB | B 16KB
  const int bid = blockIdx.x;

  if (bid < npack) {
    // ---- w2 packing (int32 -> int8), 16B-chunk grid-stride
    const long long stride = (long long)npack * 1024;
    for (long long u = (long long)bid * 1024 + threadIdx.x; u < n4w2; u += stride) {
      const int4 v = *(const int4*)(w2src + (u << 2));
      const unsigned out = (unsigned)(v.x & 0xff) | ((unsigned)(v.y & 0xff) << 8) |
                           ((unsigned)(v.z & 0xff) << 16) | ((unsigned)(v.w & 0xff) << 24);
      *(unsigned*)(w2dst + (u << 2)) = out;
    }
    return;
  }

  // ---- GEMM half (r13-exact 256x256, 16 waves 4Mx4N, wave tile 64x64)
  const int tid = threadIdx.x;
  const int lane = tid & 63, wave = tid >> 6;
  const int wavem = wave >> 2, waven = wave & 3;
  const int lh = lane & 15, sseg = lane >> 4;

  int lid;
  {
    const int o = bid - npack;
    const int nwg = gridDim.x - npack;
    const int q = nwg >> 3, r = nwg & 7;
    const int x = o & 7, p = o >> 3;
    lid = (x < r ? x * (q + 1) : r * (q + 1) + (x - r) * q) + p;
  }
  const long long t0 = (long long)(lid % gy) * 256;
  const long long n0 = (long long)(lid / gy) * 256;
  const int nk = K >> 6;
  const long long Mm1 = M - 1, Nm1 = N - 1;

  const int lr4 = lane >> 2, slot = lane & 3;
  const int rloc = wave * 16 + lr4;
  const int gslot = (slot ^ ((rloc >> 1) & 3)) << 4;
  const signed char* sp0;
  const signed char* sp1;
  {
    long long gr = t0 + rloc; if (gr > Mm1) gr = Mm1;
    sp0 = A + gr * (long long)K + gslot;
    long long gn = n0 + rloc; if (gn > Nm1) gn = Nm1;
    sp1 = Bw + gn * (long long)K + gslot;
  }
  const int d0 = wave * 1024, d1 = 16384 + wave * 1024;

#define STAGE(bi) do { \
    __builtin_amdgcn_global_load_lds(AS1C(sp0), AS3(&smem[bi][d0]), 16, 0, 0); sp0 += 64; \
    __builtin_amdgcn_global_load_lds(AS1C(sp1), AS3(&smem[bi][d1]), 16, 0, 0); sp1 += 64; \
  } while (0)

  const int xs = ((sseg ^ ((lh >> 1) & 3)) << 4);
  const int offA = wavem * 4096 + lh * 64 + xs;
  const int offB = 16384 + waven * 4096 + lh * 64 + xs;

  v4i acc[4][4] = {};

  STAGE(0);
  __syncthreads();

  int cur = 0;
  for (int kt = 0; kt < nk; ++kt) {
    if (kt + 1 < nk) STAGE(cur ^ 1);
    const char* base = smem[cur];
    v4i af[4], bf[2];
#pragma unroll
    for (int mi = 0; mi < 4; ++mi) af[mi] = *(const v4i*)(base + offA + mi * 1024);
    bf[0] = *(const v4i*)(base + offB);
    bf[1] = *(const v4i*)(base + offB + 1024);
#pragma unroll
    for (int mi = 0; mi < 4; ++mi) {
      acc[mi][0] = __builtin_amdgcn_mfma_i32_16x16x64_i8(af[mi], bf[0], acc[mi][0], 0, 0, 0);
      acc[mi][1] = __builtin_amdgcn_mfma_i32_16x16x64_i8(af[mi], bf[1], acc[mi][1], 0, 0, 0);
    }
    bf[0] = *(const v4i*)(base + offB + 2048);
    bf[1] = *(const v4i*)(base + offB + 3072);
#pragma unroll
    for (int mi = 0; mi < 4; ++mi) {
      acc[mi][2] = __builtin_amdgcn_mfma_i32_16x16x64_i8(af[mi], bf[0], acc[mi][2], 0, 0, 0);
      acc[mi][3] = __builtin_amdgcn_mfma_i32_16x16x64_i8(af[mi], bf[1], acc[mi][3], 0, 0, 0);
    }
    __syncthreads();
    cur ^= 1;
  }
#undef STAGE

  long long cidx[4]; float w4[4], bi4[4]; bool cok[4];
#pragma unroll
  for (int ni = 0; ni < 4; ++ni) {
    cidx[ni] = n0 + waven * 64 + ni * 16 + lh;
    cok[ni] = cidx[ni] < N;
    w4[ni] = cok[ni] ? wsc[cidx[ni]] : 0.f;
    bi4[ni] = cok[ni] ? bias[cidx[ni]] : 0.f;
  }
#pragma unroll
  for (int mi = 0; mi < 4; ++mi) {
#pragma unroll
    for (int j = 0; j < 4; ++j) {
      const long long t = t0 + wavem * 64 + mi * 16 + (lane >> 4) * 4 + j;
      const bool valid = t < M;
      const float st = valid ? scale_tok[t] : 0.f;
      float rowmax = 0.f;
#pragma unroll
      for (int ni = 0; ni < 4; ++ni) {
        float v = (float)acc[mi][ni][j] * st * w4[ni] + bi4[ni];
        v = __half2float(__float2half(v));  // fc1 rounds to fp16 (reference)
        const float gl = 0.5f * v * (1.f + erff(v * 0.70710678118654752f));
        rowmax = fmaxf(rowmax, fabsf(gl));
        if (valid && cok[ni]) gout[t * (long long)N + cidx[ni]] = __float2half(gl);
      }
#pragma unroll
      for (int m = 1; m < 16; m <<= 1) rowmax = fmaxf(rowmax, __shfl_xor(rowmax, m));
      if (valid && lh == 0) atomicMax(&amax[t], __float_as_uint(rowmax));
    }
  }
}

// ---------------------------------------------------------------------------
// fc2: r8-exact 128x128 / 4-wave / 32KB dbuf kernel
// ---------------------------------------------------------------------------
__device__ __forceinline__ void stage_tile(const signed char* __restrict__ g, long long ld,
                                           long long rmax, long long r0, int k0,
                                           char* lds, int tid) {
  const int wave = tid >> 6, lane = tid & 63;
#pragma unroll
  for (int p = 0; p < 2; ++p) {
    const int chunk = wave * 2 + p;
    const int row = chunk * 16 + (lane >> 2);
    const int slot = lane & 3;
    const int gslot = slot ^ ((row >> 1) & 3);
    long long rg = r0 + row;
    if (rg > rmax) rg = rmax;
    const signed char* src = g + rg * ld + (long long)k0 + gslot * 16;
    char* dst = lds + chunk * 1024;
    __builtin_amdgcn_global_load_lds(AS1C(src), AS3(dst), 16, 0, 0);
  }
}

__launch_bounds__(256, 4)
__global__ void gemm_fc2(const signed char* __restrict__ A, const signed char* __restrict__ Bw,
                         int M, int N, int K,
                         const float* __restrict__ wsc, const float* __restrict__ bias,
                         unsigned int* __restrict__ amax, float* __restrict__ fout) {
  __shared__ __align__(16) char lds[2][2][128 * 64];
  const int tid = threadIdx.x;
  const int lane = tid & 63, wave = tid >> 6;
  const int wrow = (wave >> 1) * 64, wcol = (wave & 1) * 64;

  const int gy = gridDim.y;
  int lid;
  {
    const int o = blockIdx.y * gridDim.x + blockIdx.x;
    const int nwg = gridDim.x * gy;
    const int q = nwg >> 3, r = nwg & 7;
    const int x = o & 7, p = o >> 3;
    lid = (x < r ? x * (q + 1) : r * (q + 1) + (x - r) * q) + p;
  }
  const long long t0 = (long long)(lid % gy) * 128;
  const long long n0 = (long long)(lid / gy) * 128;

  v4i acc[4][4] = {};

  stage_tile(A, K, (long long)M - 1, t0, 0, lds[0][0], tid);
  stage_tile(Bw, K, (long long)N - 1, n0, 0, lds[0][1], tid);
  __syncthreads();

  const int nk = K >> 6;
  int cur = 0;
  const int srow = lane & 15, sseg = lane >> 4;
  for (int kt = 0; kt < nk; ++kt) {
    if (kt + 1 < nk) {
      stage_tile(A, K, (long long)M - 1, t0, (kt + 1) << 6, lds[cur ^ 1][0], tid);
      stage_tile(Bw, K, (long long)N - 1, n0, (kt + 1) << 6, lds[cur ^ 1][1], tid);
    }
    v4i af[4], bf[4];
#pragma unroll
    for (int mi = 0; mi < 4; ++mi) {
      const int r = wrow + mi * 16 + srow;
      const int sl = sseg ^ ((r >> 1) & 3);
      af[mi] = *(const v4i*)&lds[cur][0][r * 64 + sl * 16];
    }
#pragma unroll
    for (int ni = 0; ni < 4; ++ni) {
      const int r = wcol + ni * 16 + srow;
      const int sl = sseg ^ ((r >> 1) & 3);
      bf[ni] = *(const v4i*)&lds[cur][1][r * 64 + sl * 16];
    }
#pragma unroll
    for (int mi = 0; mi < 4; ++mi)
#pragma unroll
      for (int ni = 0; ni < 4; ++ni)
        acc[mi][ni] = __builtin_amdgcn_mfma_i32_16x16x64_i8(af[mi], bf[ni], acc[mi][ni], 0, 0, 0);
    __syncthreads();
    cur ^= 1;
  }

#pragma unroll
  for (int mi = 0; mi < 4; ++mi) {
#pragma unroll
    for (int j = 0; j < 4; ++j) {
      const long long t = t0 + wrow + mi * 16 + (lane >> 4) * 4 + j;
      if (t < M) {
        const float am = __uint_as_float(amax[t]);
        const float st = __half2float(__float2half(am * (1.f / 127.f)));
#pragma unroll
        for (int ni = 0; ni < 4; ++ni) {
          const long long c = n0 + wcol + ni * 16 + (lane & 15);
          const float v = (float)acc[mi][ni][j] * st * wsc[c] + bias[c];
          fout[t * (long long)N + c] = __half2float(__float2half(v));
        }
      }
    }
  }
}

// ---------------------------------------------------------------------------
// per-token dynamic int8 quantization of the GELU output
// ---------------------------------------------------------------------------
__global__ void gelu_quant(const __half* __restrict__ g, const unsigned int* __restrict__ amax,
                           signed char* __restrict__ q, long long total, int I) {
  const long long nchunk = total >> 3;
  const long long stride = (long long)gridDim.x * blockDim.x;
  for (long long c = blockIdx.x * (long long)blockDim.x + threadIdx.x; c < nchunk; c += stride) {
    const long long base = c << 3;  // 8 elems, never crosses a row (I % 8 == 0)
    const int t = (int)(base / I);
    const float am = __uint_as_float(amax[t]);
    const float s = fmaxf(__half2float(__float2half(am * (1.f / 127.f))), 1e-8f);
    const float inv = 1.f / s;
    const int4 raw = *(const int4*)(g + base);
    const __half2* h2 = (const __half2*)&raw;
    union { signed char b[8]; int2 v; } u;
#pragma unroll
    for (int k = 0; k < 4; ++k) {
      const float2 f = __half22float2(h2[k]);
      const float q0 = fminf(fmaxf(rintf(f.x * inv), -128.f), 127.f);
      const float q1 = fminf(fmaxf(rintf(f.y * inv), -128.f), 127.f);
      u.b[k * 2]     = (signed char)(int)q0;
      u.b[k * 2 + 1] = (signed char)(int)q1;
    }
    *(int2*)(q + base) = u.v;
  }
}

extern "C" void kernel_launch(void* const* d_in, const int* in_sizes, int n_in,
                              void* d_out, int out_size, void* d_ws, size_t ws_size,
                              hipStream_t stream) {
  const int* hs = (const int*)d_in[0];
  const float* scale_in = (const float*)d_in[1];   // fp16 in reference -> f32 buffer
  const int* w1 = (const int*)d_in[2];
  const float* w1s = (const float*)d_in[3];
  const float* b1 = (const float*)d_in[4];
  const int* w2 = (const int*)d_in[5];
  const float* w2s = (const float*)d_in[6];
  const float* b2 = (const float*)d_in[7];

  const int T = in_sizes[1];        // 2050
  const int I = in_sizes[3];        // 12800
  const int H = in_sizes[6];        // 3200

  char* ws = (char*)d_ws;
  unsigned int* amax = (unsigned int*)ws;                    // T u32 (16KB pad)
  signed char* px  = (signed char*)(ws + 16384);             // T*H
  signed char* pw1 = px + (size_t)T * H;                     // I*H
  signed char* pw2 = pw1 + (size_t)I * H;                    // H*I
  __half* gbuf = (__half*)(pw2 + (size_t)H * I);             // T*I fp16
  signed char* qbuf = (signed char*)(gbuf + (size_t)T * I);  // T*I

  const long long nx = (long long)T * H, nw1 = (long long)I * H, nw2 = (long long)H * I;

  // pack x + w1 (+ amax zero) — must precede fc1
  pack1<<<2048, 256, 0, stream>>>(hs, w1, px, pw1, amax, nx, nw1, T);

  // fc1 (256x256, 16 waves) fused with w2 packing; 62 + 450 = 512 blocks
  // = exact 2-blocks/CU co-residency (no GEMM tail).
  const int NPACK = 62;
  const int gy1 = (T + 255) / 256;                 // 9
  const int gemmBlocks = (I / 256) * gy1;          // 450
  fc1_fused<<<NPACK + gemmBlocks, 1024, 0, stream>>>(
      px, pw1, T, I, H, scale_in, w1s, b1, gbuf, amax,
      w2, pw2, nw2 >> 2, NPACK, gy1);

  gelu_quant<<<2048, 256, 0, stream>>>(gbuf, amax, qbuf, (long long)T * I, I);

  // fc2: r8-exact 128x128, grid 25 x 17 = 425 blocks
  dim3 g2(H / 128, (T + 127) / 128);
  gemm_fc2<<<g2, 256, 0, stream>>>(qbuf, pw2, T, H, I, w2s, b2, amax, (float*)d_out);
}